// Round 1
// baseline (828.273 us; speedup 1.0000x reference)
//
#include <hip/hip_runtime.h>
#include <hip/hip_bf16.h>

// Problem constants (from reference): N,C,K,P,Q,PS = 32,128,128,64,64,3
#define NN 32
#define CC 128
#define KK 128
#define PP 64
#define QQ 64

// Baseline: direct 3x3 conv, fp32 vector ALU.
// block = 64(q) x 4(p-rows) = 256 threads; each thread computes KT=8 output
// channels for its (n,p,q). W index is block-uniform -> compiler emits s_load
// (scalar cache), x loads are q-coalesced and the 3x3 patch is register-reused
// across the 8 k's.
constexpr int KT = 8;

__global__ __launch_bounds__(256) void conv3x3_f32_kernel(
    const float* __restrict__ x,     // [N][C][P][Q]
    const float* __restrict__ W,     // [K][C*9]  (c-major, then kh, kw)
    const float* __restrict__ per,   // [N][K][P][Q]
    float* __restrict__ out)         // [N][K][P][Q]
{
    const int q  = threadIdx.x;            // 0..63
    const int pr = threadIdx.y;            // 0..3
    const int p  = blockIdx.x * 4 + pr;    // 0..63
    const int k0 = blockIdx.y * KT;        // 0..120
    const int n  = blockIdx.z;             // 0..31

    float acc[KT];
#pragma unroll
    for (int i = 0; i < KT; ++i) acc[i] = 0.f;

    const float* xn = x + (size_t)n * CC * PP * QQ;

    for (int c = 0; c < CC; ++c) {
        const float* xc = xn + (size_t)c * PP * QQ;

        // 3x3 input patch around (p,q), zero-padded at borders.
        float xv[3][3];
#pragma unroll
        for (int dp = 0; dp < 3; ++dp) {
            const int pp = p + dp - 1;
#pragma unroll
            for (int dq = 0; dq < 3; ++dq) {
                const int qq = q + dq - 1;
                const bool ok = ((unsigned)pp < (unsigned)PP) && ((unsigned)qq < (unsigned)QQ);
                xv[dp][dq] = ok ? xc[pp * QQ + qq] : 0.f;
            }
        }

        // W[k][c*9 + kh*3 + kw] — block-uniform address -> scalar loads.
        const float* wc = W + c * 9;
#pragma unroll
        for (int kk = 0; kk < KT; ++kk) {
            const float* wk = wc + (size_t)(k0 + kk) * (CC * 9);
            float a = acc[kk];
#pragma unroll
            for (int dp = 0; dp < 3; ++dp)
#pragma unroll
                for (int dq = 0; dq < 3; ++dq)
                    a = fmaf(xv[dp][dq], wk[dp * 3 + dq], a);
            acc[kk] = a;
        }
    }

#pragma unroll
    for (int kk = 0; kk < KT; ++kk) {
        const size_t oi = (((size_t)n * KK + (k0 + kk)) * PP + p) * QQ + q;
        out[oi] = acc[kk] + per[oi];
    }
}

extern "C" void kernel_launch(void* const* d_in, const int* in_sizes, int n_in,
                              void* d_out, int out_size, void* d_ws, size_t ws_size,
                              hipStream_t stream) {
    const float* x   = (const float*)d_in[0];  // 32*128*64*64
    const float* W   = (const float*)d_in[1];  // 128*1152
    const float* per = (const float*)d_in[2];  // 32*128*64*64
    float* out = (float*)d_out;

    dim3 block(QQ, 4, 1);                       // 256 threads
    dim3 grid(PP / 4, KK / KT, NN);             // 16 x 16 x 32
    conv3x3_f32_kernel<<<grid, block, 0, stream>>>(x, W, per, out);
}

// Round 2
// 277.514 us; speedup vs baseline: 2.9846x; 2.9846x over previous
//
#include <hip/hip_runtime.h>
#include <hip/hip_bf16.h>

// N,C,K,P,Q,PS = 32,128,128,64,64,3
#define NN 32
#define CCH 128
#define KK 128
#define PP 64
#define QQ 64

typedef __bf16 bf16x8 __attribute__((ext_vector_type(8)));
typedef float f32x16 __attribute__((ext_vector_type(16)));

// Workspace layout:
//   xT: [N][P][Q][C] bf16   = 32*64*64*128*2 = 33,554,432 B
//   Wf: [8 cc][9 t][4 kb][64 lane][8 bf16]  = 294,912 B (MFMA fragment order)
#define XT_ELEMS (32ull * 64 * 64 * 128)

// ---------------- prep 1: x (NCHW f32) -> xT (NPQC bf16) ----------------
// block 256 = 16 c-chunks x 16 q; writes are fully coalesced 16B/lane.
__global__ __launch_bounds__(256) void prep_x(const float* __restrict__ x,
                                              __bf16* __restrict__ xT) {
    const int t  = threadIdx.x;
    const int cc = t & 15;        // which 8-c chunk
    const int qi = t >> 4;        // 0..15
    const int q  = blockIdx.x * 16 + qi;
    const int p  = blockIdx.y;
    const int n  = blockIdx.z;

    bf16x8 o;
#pragma unroll
    for (int i = 0; i < 8; ++i) {
        float v = x[(((size_t)n * CCH + cc * 8 + i) * PP + p) * QQ + q];
        o[i] = (__bf16)v;
    }
    *(bf16x8*)(xT + (((size_t)n * PP + p) * QQ + q) * CCH + cc * 8) = o;
}

// ---------------- prep 2: W (K x C*9 f32) -> Wf fragment order ----------------
// Wf chunk id = ((cc*9 + t)*4 + kb)*64 + lane ; chunk = 8 bf16 (16 B).
// Fragment semantics: k = kb*32 + (lane&31), c = cc*16 + (lane>>5)*8 + j.
__global__ __launch_bounds__(256) void prep_w(const float* __restrict__ W,
                                              __bf16* __restrict__ Wf) {
    const int id = blockIdx.x * 256 + threadIdx.x;  // 8*9*4*64 = 18432
    const int lane = id & 63;
    const int r1   = id >> 6;
    const int kb   = r1 & 3;
    const int r2   = r1 >> 2;
    const int t    = r2 % 9;
    const int cc   = r2 / 9;

    const int k  = kb * 32 + (lane & 31);
    const int c0 = cc * 16 + (lane >> 5) * 8;

    bf16x8 o;
#pragma unroll
    for (int j = 0; j < 8; ++j)
        o[j] = (__bf16)W[(size_t)k * (CCH * 9) + (size_t)(c0 + j) * 9 + t];
    ((bf16x8*)Wf)[id] = o;
}

// ---------------- main: implicit GEMM conv + perturb add ----------------
// Workgroup: (n, 2 p-rows, 64 q) x 128 k. 4 waves: wave = (pb = w>>1, kbs = w&1).
// A = W (m-dim = k) from LDS; B = xT (col = q) from global; D cols = q -> coalesced.
__global__ __launch_bounds__(256) void conv_main(const __bf16* __restrict__ xT,
                                                 const __bf16* __restrict__ Wf,
                                                 const float* __restrict__ per,
                                                 float* __restrict__ out) {
    __shared__ __align__(16) __bf16 wlds[9 * 4 * 64 * 8];  // 36,864 B

    const int tid  = threadIdx.x;
    const int lane = tid & 63;
    const int w    = tid >> 6;
    const int pb   = w >> 1;   // which p-row of the pair
    const int kbs  = w & 1;    // which pair of k-blocks
    const int p0   = blockIdx.x * 2;
    const int n    = blockIdx.y;
    const int m    = lane & 31;
    const int half = lane >> 5;

    f32x16 acc[2][2];
#pragma unroll
    for (int i = 0; i < 2; ++i)
#pragma unroll
        for (int j = 0; j < 2; ++j)
#pragma unroll
            for (int e = 0; e < 16; ++e) acc[i][j][e] = 0.f;

    bf16x8 bzero;
#pragma unroll
    for (int e = 0; e < 8; ++e) bzero[e] = (__bf16)0.f;

    const __bf16* xrow = xT + (size_t)n * PP * QQ * CCH;

    for (int cc = 0; cc < 8; ++cc) {
        __syncthreads();
        // stage Wf[cc] (36,864 B) -> LDS, linear async copy, 16 B/lane
        {
            const char* g = (const char*)(Wf + (size_t)cc * 18432);
            char*       l = (char*)wlds;
#pragma unroll
            for (int it = 0; it < 9; ++it) {
                int off = (it * 256 + tid) * 16;
                __builtin_amdgcn_global_load_lds(
                    (const __attribute__((address_space(1))) unsigned int*)(g + off),
                    (__attribute__((address_space(3))) unsigned int*)(l + off),
                    16, 0, 0);
            }
        }
        __syncthreads();

        const int c0 = cc * 16 + half * 8;
#pragma unroll
        for (int t = 0; t < 9; ++t) {
            const int dp = t / 3 - 1, dq = t % 3 - 1;
            const int prow = p0 + pb + dp;
            if ((unsigned)prow >= (unsigned)PP) continue;  // wave-uniform skip

            // A frags (W) from LDS — linear, conflict-free ds_read_b128
            bf16x8 a0 = ((bf16x8*)wlds)[(t * 4 + kbs * 2 + 0) * 64 + lane];
            bf16x8 a1 = ((bf16x8*)wlds)[(t * 4 + kbs * 2 + 1) * 64 + lane];

            // B frags (xT) from global — 16 B/lane, aligned
            bf16x8 b0, b1;
            {
                int q = 0 * 32 + m + dq;
                b0 = ((unsigned)q < (unsigned)QQ)
                         ? *(const bf16x8*)(xrow + ((size_t)prow * QQ + q) * CCH + c0)
                         : bzero;
            }
            {
                int q = 1 * 32 + m + dq;
                b1 = ((unsigned)q < (unsigned)QQ)
                         ? *(const bf16x8*)(xrow + ((size_t)prow * QQ + q) * CCH + c0)
                         : bzero;
            }

            acc[0][0] = __builtin_amdgcn_mfma_f32_32x32x16_bf16(a0, b0, acc[0][0], 0, 0, 0);
            acc[0][1] = __builtin_amdgcn_mfma_f32_32x32x16_bf16(a0, b1, acc[0][1], 0, 0, 0);
            acc[1][0] = __builtin_amdgcn_mfma_f32_32x32x16_bf16(a1, b0, acc[1][0], 0, 0, 0);
            acc[1][1] = __builtin_amdgcn_mfma_f32_32x32x16_bf16(a1, b1, acc[1][1], 0, 0, 0);
        }
    }

    // Epilogue: D col = q (coalesced), row = k. Fused perturb add.
    const int prow = p0 + pb;
#pragma unroll
    for (int kbi = 0; kbi < 2; ++kbi) {
#pragma unroll
        for (int mb = 0; mb < 2; ++mb) {
            f32x16 v = acc[kbi][mb];
#pragma unroll
            for (int r = 0; r < 16; ++r) {
                int krow = (r & 3) + 8 * (r >> 2) + 4 * half;
                int k    = (kbs * 2 + kbi) * 32 + krow;
                int q    = mb * 32 + m;
                size_t oi = (((size_t)n * KK + k) * PP + prow) * QQ + q;
                out[oi] = v[r] + per[oi];
            }
        }
    }
}

extern "C" void kernel_launch(void* const* d_in, const int* in_sizes, int n_in,
                              void* d_out, int out_size, void* d_ws, size_t ws_size,
                              hipStream_t stream) {
    const float* x   = (const float*)d_in[0];  // [32][128][64][64]
    const float* W   = (const float*)d_in[1];  // [128][1152]
    const float* per = (const float*)d_in[2];  // [32][128][64][64]
    float* out = (float*)d_out;

    __bf16* xT = (__bf16*)d_ws;
    __bf16* Wf = (__bf16*)((char*)d_ws + XT_ELEMS * 2);

    // prep x: grid (Q/16, P, N), block 256
    prep_x<<<dim3(QQ / 16, PP, NN), 256, 0, stream>>>(x, xT);
    // prep W: 18432 threads
    prep_w<<<dim3(72), 256, 0, stream>>>(W, Wf);
    // main: grid (P/2, N), block 256
    conv_main<<<dim3(PP / 2, NN), 256, 0, stream>>>(xT, Wf, per, out);
}

// Round 3
// 244.714 us; speedup vs baseline: 3.3847x; 1.1340x over previous
//
#include <hip/hip_runtime.h>
#include <hip/hip_bf16.h>

// N,C,K,P,Q,PS = 32,128,128,64,64,3
#define NN 32
#define CCH 128
#define KK 128
#define PP 64
#define QQ 64

typedef __bf16 bf16x8 __attribute__((ext_vector_type(8)));
typedef float f32x16 __attribute__((ext_vector_type(16)));
typedef float f32x4 __attribute__((ext_vector_type(4)));

// Workspace:
//   xT: [N][P][Q][C] bf16 = 33,554,432 B
//   Wf: [8 cc][9 t][4 kb][64 lane][8 bf16] = 294,912 B
#define XT_ELEMS (32ull * 64 * 64 * 128)

// ---------- prep 1: x (NCHW f32) -> xT (NPQC bf16), LDS transpose ----------
// One block per (p, n): reads 128c x 64q tile coalesced along q, writes
// coalesced along c (16 B/lane).
__global__ __launch_bounds__(256) void prep_x(const float* __restrict__ x,
                                              __bf16* __restrict__ xT) {
    __shared__ float tile[128 * 68];  // pitch 68 floats (272 B, 16B-aligned)
    const int t = threadIdx.x;
    const int p = blockIdx.x;
    const int n = blockIdx.y;

    // read: 128 rows (c) x 64 floats (q) = 2048 float4, 8 passes
#pragma unroll
    for (int pass = 0; pass < 8; ++pass) {
        int idx = pass * 256 + t;
        int qf = idx & 15;       // float4 index along q
        int c  = idx >> 4;
        f32x4 v = *(const f32x4*)(x + (((size_t)n * CCH + c) * PP + p) * QQ + qf * 4);
        *(f32x4*)(tile + c * 68 + qf * 4) = v;
    }
    __syncthreads();

    // write: 64 q x 16 c-chunks (8 c each) = 1024 chunks, 4 passes
#pragma unroll
    for (int pass = 0; pass < 4; ++pass) {
        int idx = pass * 256 + t;
        int jc = idx & 15;
        int q  = idx >> 4;
        bf16x8 o;
#pragma unroll
        for (int j = 0; j < 8; ++j) o[j] = (__bf16)tile[(jc * 8 + j) * 68 + q];
        *(bf16x8*)(xT + (((size_t)n * PP + p) * QQ + q) * CCH + jc * 8) = o;
    }
}

// ---------- prep 2: W -> Wf fragment order (unchanged, verified) ----------
// frag: k = kb*32 + (lane&31), c = cc*16 + (lane>>5)*8 + j, tap t.
__global__ __launch_bounds__(256) void prep_w(const float* __restrict__ W,
                                              __bf16* __restrict__ Wf) {
    const int id = blockIdx.x * 256 + threadIdx.x;  // 18432
    const int lane = id & 63;
    const int r1   = id >> 6;
    const int kb   = r1 & 3;
    const int r2   = r1 >> 2;
    const int t    = r2 % 9;
    const int cc   = r2 / 9;

    const int k  = kb * 32 + (lane & 31);
    const int c0 = cc * 16 + (lane >> 5) * 8;

    bf16x8 o;
#pragma unroll
    for (int j = 0; j < 8; ++j)
        o[j] = (__bf16)W[(size_t)k * (CCH * 9) + (size_t)(c0 + j) * 9 + t];
    ((bf16x8*)Wf)[id] = o;
}

// ---------- main: implicit GEMM conv + perturb add ----------
// Block: 4 p-rows x 64 q x 128 k. Wave w: kbs = w&1 (2 k-blocks), pb2 = w>>1
// (which p-row pair). acc[oi][kb][qb] = 8 x f32x16 = 128 AGPRs.
// Per staged pair of c-chunks: iterate input rows r = pbase-1..pbase+2;
// row's 6 B-frags feed up to 24 MFMAs; A-frags reused across consecutive r.
__global__ __launch_bounds__(256, 2) void conv_main(const __bf16* __restrict__ xT,
                                                    const __bf16* __restrict__ Wf,
                                                    const float* __restrict__ per,
                                                    float* __restrict__ out) {
    __shared__ __align__(16) __bf16 wlds[2 * 9 * 4 * 64 * 8];  // 73,728 B

    const int tid  = threadIdx.x;
    const int lane = tid & 63;
    const int w    = tid >> 6;
    const int kbs  = w & 1;
    const int pb2  = w >> 1;
    const int n    = blockIdx.y;
    const int pbase = blockIdx.x * 4 + pb2 * 2;
    const int m    = lane & 31;
    const int half = lane >> 5;

    f32x16 acc[2][2][2];  // [oi][kb][qb]
#pragma unroll
    for (int a = 0; a < 2; ++a)
#pragma unroll
        for (int b = 0; b < 2; ++b)
#pragma unroll
            for (int c = 0; c < 2; ++c)
#pragma unroll
                for (int e = 0; e < 16; ++e) acc[a][b][c][e] = 0.f;

    bf16x8 bzero;
#pragma unroll
    for (int e = 0; e < 8; ++e) bzero[e] = (__bf16)0.f;

    // per-lane q byte-offsets + validity for the 6 (dq,qb) combos
    int qoff[3][2];
    bool qok[3][2];
#pragma unroll
    for (int dq = 0; dq < 3; ++dq)
#pragma unroll
        for (int qb = 0; qb < 2; ++qb) {
            int q = qb * 32 + m + dq - 1;
            qok[dq][qb] = (unsigned)q < (unsigned)QQ;
            int qc = q < 0 ? 0 : (q > 63 ? 63 : q);
            qoff[dq][qb] = qc * (CCH * 2) + half * 16;
        }

    const char* xrow = (const char*)(xT + (size_t)n * PP * QQ * CCH);

    for (int ccp = 0; ccp < 4; ++ccp) {
        __syncthreads();
        // stage 2 c-chunks of Wf (73,728 B), linear 16 B/lane async copy
        {
            const char* g = (const char*)Wf + (size_t)ccp * 73728;
            char*       l = (char*)wlds;
#pragma unroll
            for (int it = 0; it < 18; ++it) {
                int off = (it * 256 + tid) * 16;
                __builtin_amdgcn_global_load_lds(
                    (const __attribute__((address_space(1))) unsigned int*)(g + off),
                    (__attribute__((address_space(3))) unsigned int*)(l + off),
                    16, 0, 0);
            }
        }
        __syncthreads();

#pragma unroll
        for (int s = 0; s < 2; ++s) {
            const int cc = ccp * 2 + s;
            const int cboff = cc * 32;  // byte offset of 16-c chunk in a q-row

            bf16x8 a_cur[3][2], a_prev[3][2];
#pragma unroll
            for (int ri = 0; ri < 4; ++ri) {
                const int r = pbase - 1 + ri;
                const bool rok = (unsigned)r < (unsigned)PP;

                // B frags for input row r
                bf16x8 b[3][2];
                if (rok) {
                    const char* rbase = xrow + (size_t)r * (QQ * CCH * 2) + cboff;
#pragma unroll
                    for (int dq = 0; dq < 3; ++dq)
#pragma unroll
                        for (int qb = 0; qb < 2; ++qb) {
                            bf16x8 v = *(const bf16x8*)(rbase + qoff[dq][qb]);
                            b[dq][qb] = qok[dq][qb] ? v : bzero;
                        }
                } else {
#pragma unroll
                    for (int dq = 0; dq < 3; ++dq)
#pragma unroll
                        for (int qb = 0; qb < 2; ++qb) b[dq][qb] = bzero;
                }

                // A frags for tap-row: t = ri*3 + dq (used by oi=0 now, oi=1 next ri)
                if (ri < 3) {
#pragma unroll
                    for (int dq = 0; dq < 3; ++dq)
#pragma unroll
                        for (int kb = 0; kb < 2; ++kb)
                            a_cur[dq][kb] = ((bf16x8*)wlds)[((s * 9 + ri * 3 + dq) * 4 +
                                                             kbs * 2 + kb) * 64 + lane];
                }

                if (ri >= 1) {  // output row pbase+1, A = a_prev
#pragma unroll
                    for (int dq = 0; dq < 3; ++dq)
#pragma unroll
                        for (int kb = 0; kb < 2; ++kb)
#pragma unroll
                            for (int qb = 0; qb < 2; ++qb)
                                acc[1][kb][qb] = __builtin_amdgcn_mfma_f32_32x32x16_bf16(
                                    a_prev[dq][kb], b[dq][qb], acc[1][kb][qb], 0, 0, 0);
                }
                if (ri < 3) {  // output row pbase, A = a_cur
#pragma unroll
                    for (int dq = 0; dq < 3; ++dq)
#pragma unroll
                        for (int kb = 0; kb < 2; ++kb)
#pragma unroll
                            for (int qb = 0; qb < 2; ++qb)
                                acc[0][kb][qb] = __builtin_amdgcn_mfma_f32_32x32x16_bf16(
                                    a_cur[dq][kb], b[dq][qb], acc[0][kb][qb], 0, 0, 0);
                }

                if (ri < 3) {
#pragma unroll
                    for (int dq = 0; dq < 3; ++dq)
#pragma unroll
                        for (int kb = 0; kb < 2; ++kb) a_prev[dq][kb] = a_cur[dq][kb];
                }
            }
        }
    }

    // Epilogue: D col = q (coalesced), row = k. Fused perturb add.
#pragma unroll
    for (int oi = 0; oi < 2; ++oi) {
        const int prow = pbase + oi;
#pragma unroll
        for (int kbi = 0; kbi < 2; ++kbi) {
#pragma unroll
            for (int qb = 0; qb < 2; ++qb) {
                f32x16 v = acc[oi][kbi][qb];
#pragma unroll
                for (int r = 0; r < 16; ++r) {
                    int krow = (r & 3) + 8 * (r >> 2) + 4 * half;
                    int k    = (kbs * 2 + kbi) * 32 + krow;
                    int q    = qb * 32 + m;
                    size_t oidx = (((size_t)n * KK + k) * PP + prow) * QQ + q;
                    out[oidx] = v[r] + per[oidx];
                }
            }
        }
    }
}

extern "C" void kernel_launch(void* const* d_in, const int* in_sizes, int n_in,
                              void* d_out, int out_size, void* d_ws, size_t ws_size,
                              hipStream_t stream) {
    const float* x   = (const float*)d_in[0];  // [32][128][64][64]
    const float* W   = (const float*)d_in[1];  // [128][1152]
    const float* per = (const float*)d_in[2];  // [32][128][64][64]
    float* out = (float*)d_out;

    __bf16* xT = (__bf16*)d_ws;
    __bf16* Wf = (__bf16*)((char*)d_ws + XT_ELEMS * 2);

    prep_x<<<dim3(PP, NN), 256, 0, stream>>>(x, xT);
    prep_w<<<dim3(72), 256, 0, stream>>>(W, Wf);
    conv_main<<<dim3(PP / 4, NN), 256, 0, stream>>>(xT, Wf, per, out);
}

// Round 4
// 209.381 us; speedup vs baseline: 3.9558x; 1.1687x over previous
//
#include <hip/hip_runtime.h>
#include <hip/hip_bf16.h>

// N,C,K,P,Q,PS = 32,128,128,64,64,3
#define NN 32
#define CCH 128
#define KK 128
#define PP 64
#define QQ 64

typedef __bf16 bf16x8 __attribute__((ext_vector_type(8)));
typedef float f32x16 __attribute__((ext_vector_type(16)));
typedef float f32x4 __attribute__((ext_vector_type(4)));

// Workspace:
//   xT: [N][8 cc][P][Q][16 c] bf16 = 33,554,432 B   (c-chunk-major!)
//   Wf: [8 cc][9 t][4 kb][64 lane][8 bf16] = 294,912 B
#define XT_ELEMS (32ull * 64 * 64 * 128)

// ---------- prep 1: x (NCHW f32) -> xT ([n][cc][p][q][16c] bf16) ----------
// LDS tile 128c x 64q, XOR-swizzled: element (c,q) lives at tile[c*64 + (q ^ key(c))],
// key(c) = 4*((c>>3)&15). Write: f32x4 (key mult of 4 keeps groups contiguous).
// Read banks: per instr lanes have q spanning 0..63 with key varying by half ->
// exactly 2 lanes/bank (free). Old pitch-68 version was 16-way conflicted.
__global__ __launch_bounds__(256) void prep_x(const float* __restrict__ x,
                                              __bf16* __restrict__ xT) {
    __shared__ float tile[128 * 64];
    const int t = threadIdx.x;
    const int p = blockIdx.x;
    const int n = blockIdx.y;

    // read: 128 c-rows x 16 float4 along q, coalesced 256 B per 16 lanes
#pragma unroll
    for (int pass = 0; pass < 8; ++pass) {
        int idx = pass * 256 + t;
        int qf = idx & 15;
        int c  = idx >> 4;
        f32x4 v = *(const f32x4*)(x + (((size_t)n * CCH + c) * PP + p) * QQ + qf * 4);
        int key = ((c >> 3) & 15) * 4;
        *(f32x4*)(tile + c * 64 + ((qf * 4) ^ key)) = v;
    }
    __syncthreads();

    // write: 4 passes; pass covers 2 c-chunks x 64 q x 2 halves = 256 threads.
    // Global writes fully contiguous (4 KB per 128 consecutive threads).
#pragma unroll
    for (int pass = 0; pass < 4; ++pass) {
        int cc   = pass * 2 + (t >> 7);
        int rem  = t & 127;
        int q    = rem >> 1;
        int half = rem & 1;
        int c0   = cc * 16 + half * 8;
        int key  = ((c0 >> 3) & 15) * 4;  // constant across j (c0 mult of 8)
        bf16x8 o;
#pragma unroll
        for (int j = 0; j < 8; ++j) o[j] = (__bf16)tile[(c0 + j) * 64 + (q ^ key)];
        *(bf16x8*)(xT + ((((size_t)n * 8 + cc) * PP + p) * QQ + q) * 16 + half * 8) = o;
    }
}

// ---------- prep 2: W -> Wf fragment order (verified) ----------
// frag: k = kb*32 + (lane&31), c = cc*16 + (lane>>5)*8 + j, tap t.
__global__ __launch_bounds__(256) void prep_w(const float* __restrict__ W,
                                              __bf16* __restrict__ Wf) {
    const int id = blockIdx.x * 256 + threadIdx.x;  // 18432
    const int lane = id & 63;
    const int r1   = id >> 6;
    const int kb   = r1 & 3;
    const int r2   = r1 >> 2;
    const int t    = r2 % 9;
    const int cc   = r2 / 9;

    const int k  = kb * 32 + (lane & 31);
    const int c0 = cc * 16 + (lane >> 5) * 8;

    bf16x8 o;
#pragma unroll
    for (int j = 0; j < 8; ++j)
        o[j] = (__bf16)W[(size_t)k * (CCH * 9) + (size_t)(c0 + j) * 9 + t];
    ((bf16x8*)Wf)[id] = o;
}

// ---------- main: implicit GEMM conv, both operands LDS-staged ----------
// Block: 4 p-rows x 64 q x 128 k. Wave: kbs = w&1 (2 k-blocks), pb2 = w>>1.
// Per cc (16 c): stage W chunk (36,864 B) + 6 x-rows (pitch 2112 B: 66 q-slots,
// slot 0 / 65 are permanent zeros -> no q-edge masking in inner loop).
// B from ds_read_b128 (even bank spread), A from ds_read_b128 (lane*16, free).
#define XPITCH 2112  // bytes per padded x row in LDS (66 * 32)
__global__ __launch_bounds__(256, 2) void conv_main(const __bf16* __restrict__ xT,
                                                    const __bf16* __restrict__ Wf,
                                                    const float* __restrict__ per,
                                                    float* __restrict__ out) {
    __shared__ __align__(16) char wlds[36864];
    __shared__ __align__(16) char xlds[6 * XPITCH];  // 12,672 B

    const int tid  = threadIdx.x;
    const int lane = tid & 63;
    const int w    = tid >> 6;
    const int kbs  = w & 1;
    const int pb2  = w >> 1;
    const int n    = blockIdx.y;
    const int p0   = blockIdx.x * 4;
    const int m    = lane & 31;
    const int half = lane >> 5;

    // zero the pad columns (q=-1 and q=64 slots), once; staging never touches them
    if (tid < 24) {
        int row = tid >> 2, part = tid & 3;
        int off = row * XPITCH + (part >> 1) * 2080 + (part & 1) * 16;
        *(f32x4*)(xlds + off) = f32x4{0.f, 0.f, 0.f, 0.f};
    }

    f32x16 acc[2][2][2];  // [oi][kb][qb]
#pragma unroll
    for (int a = 0; a < 2; ++a)
#pragma unroll
        for (int b = 0; b < 2; ++b)
#pragma unroll
            for (int c = 0; c < 2; ++c)
#pragma unroll
                for (int e = 0; e < 16; ++e) acc[a][b][c][e] = 0.f;

    const char* xb = (const char*)xT + ((size_t)n * 8) * PP * QQ * 32;  // + cc*PP*QQ*32

    for (int cc = 0; cc < 8; ++cc) {
        __syncthreads();
        // stage W chunk: 36,864 B = 9 x (256 threads x 16 B), linear
        {
            const char* g = (const char*)Wf + (size_t)cc * 36864;
#pragma unroll
            for (int it = 0; it < 9; ++it) {
                int off = (it * 256 + tid) * 16;
                __builtin_amdgcn_global_load_lds(
                    (const __attribute__((address_space(1))) unsigned int*)(g + off),
                    (__attribute__((address_space(3))) unsigned int*)(wlds + off),
                    16, 0, 0);
            }
        }
        // stage 6 x-rows (p0-1 .. p0+4, clamped; OOB rows' MFMAs are skipped)
        {
            const char* gx = xb + (size_t)cc * (PP * QQ * 32);
#pragma unroll
            for (int it = 0; it < 3; ++it) {
                int gi  = it * 256 + tid;       // 0..767; 128 chunks/row
                int row = gi >> 7;              // wave-uniform (64 | 128)
                int wi  = (gi & 127) * 16;
                int r   = p0 - 1 + row;
                int rc  = r < 0 ? 0 : (r > 63 ? 63 : r);
                __builtin_amdgcn_global_load_lds(
                    (const __attribute__((address_space(1))) unsigned int*)(gx + (size_t)rc * 2048 + wi),
                    (__attribute__((address_space(3))) unsigned int*)(xlds + row * XPITCH + 32 + wi),
                    16, 0, 0);
            }
        }
        __syncthreads();

        bf16x8 a_cur[3][2], a_prev[3][2];
#pragma unroll
        for (int ri = 0; ri < 4; ++ri) {
            const int rr = pb2 * 2 + ri;          // xlds row 0..5
            const int r  = p0 + pb2 * 2 + ri - 1; // global input row
            const bool rok = ((unsigned)r < (unsigned)PP);  // wave-uniform

            // B frags for input row rr: q_in+1 = qb*32 + m + dq  (pad handles edges)
            bf16x8 b[3][2];
            if (rok) {
                const char* rbase = xlds + rr * XPITCH + half * 16;
#pragma unroll
                for (int dq = 0; dq < 3; ++dq)
#pragma unroll
                    for (int qb = 0; qb < 2; ++qb)
                        b[dq][qb] = *(const bf16x8*)(rbase + (qb * 32 + m + dq) * 32);
            }

            // A frags for tap row ri (consumed by oi=0 now, oi=1 at ri+1)
            if (ri < 3) {
#pragma unroll
                for (int dq = 0; dq < 3; ++dq)
#pragma unroll
                    for (int kb = 0; kb < 2; ++kb)
                        a_cur[dq][kb] = ((const bf16x8*)wlds)[((ri * 3 + dq) * 4 +
                                                               kbs * 2 + kb) * 64 + lane];
            }

            if (rok) {
                if (ri >= 1) {
#pragma unroll
                    for (int dq = 0; dq < 3; ++dq)
#pragma unroll
                        for (int kb = 0; kb < 2; ++kb)
#pragma unroll
                            for (int qb = 0; qb < 2; ++qb)
                                acc[1][kb][qb] = __builtin_amdgcn_mfma_f32_32x32x16_bf16(
                                    a_prev[dq][kb], b[dq][qb], acc[1][kb][qb], 0, 0, 0);
                }
                if (ri < 3) {
#pragma unroll
                    for (int dq = 0; dq < 3; ++dq)
#pragma unroll
                        for (int kb = 0; kb < 2; ++kb)
#pragma unroll
                            for (int qb = 0; qb < 2; ++qb)
                                acc[0][kb][qb] = __builtin_amdgcn_mfma_f32_32x32x16_bf16(
                                    a_cur[dq][kb], b[dq][qb], acc[0][kb][qb], 0, 0, 0);
                }
            }

            if (ri < 3) {
#pragma unroll
                for (int dq = 0; dq < 3; ++dq)
#pragma unroll
                    for (int kb = 0; kb < 2; ++kb) a_prev[dq][kb] = a_cur[dq][kb];
            }
        }
    }

    // Epilogue: D col = q (coalesced), row = k; fused perturb add.
#pragma unroll
    for (int oi = 0; oi < 2; ++oi) {
        const int prow = p0 + pb2 * 2 + oi;
#pragma unroll
        for (int kbi = 0; kbi < 2; ++kbi) {
#pragma unroll
            for (int qb = 0; qb < 2; ++qb) {
                f32x16 v = acc[oi][kbi][qb];
#pragma unroll
                for (int r = 0; r < 16; ++r) {
                    int krow = (r & 3) + 8 * (r >> 2) + 4 * half;
                    int k    = (kbs * 2 + kbi) * 32 + krow;
                    int q    = qb * 32 + m;
                    size_t oidx = (((size_t)n * KK + k) * PP + prow) * QQ + q;
                    out[oidx] = v[r] + per[oidx];
                }
            }
        }
    }
}

extern "C" void kernel_launch(void* const* d_in, const int* in_sizes, int n_in,
                              void* d_out, int out_size, void* d_ws, size_t ws_size,
                              hipStream_t stream) {
    const float* x   = (const float*)d_in[0];  // [32][128][64][64]
    const float* W   = (const float*)d_in[1];  // [128][1152]
    const float* per = (const float*)d_in[2];  // [32][128][64][64]
    float* out = (float*)d_out;

    __bf16* xT = (__bf16*)d_ws;
    __bf16* Wf = (__bf16*)((char*)d_ws + XT_ELEMS * 2);

    prep_x<<<dim3(PP, NN), 256, 0, stream>>>(x, xT);
    prep_w<<<dim3(72), 256, 0, stream>>>(W, Wf);
    conv_main<<<dim3(PP / 4, NN), 256, 0, stream>>>(xT, Wf, per, out);
}